// Round 20
// baseline (144.688 us; speedup 1.0000x reference)
//
#include <hip/hip_runtime.h>
#include <hip/hip_bf16.h>

namespace {

constexpr int B = 4, S = 2048, D = 1024, H = 16, DH = 64;
constexpr int NT = S / 32;  // 64 kv tiles

typedef __attribute__((ext_vector_type(8))) short short8;
typedef __attribute__((ext_vector_type(4))) short short4v;
typedef __attribute__((ext_vector_type(2))) unsigned uint2v;
typedef __attribute__((ext_vector_type(4))) float f32x4;
typedef __attribute__((ext_vector_type(16))) float f32x16;

union U8 { unsigned u[4]; short8 s; };
union BF2 { __hip_bfloat162 h; unsigned u; };

__device__ __forceinline__ short f2bf(float f) {
  unsigned u = __builtin_bit_cast(unsigned, f);
  u = (u + 0x7fffu + ((u >> 16) & 1u)) >> 16;
  return (short)u;
}

__device__ __forceinline__ float bf2f(short s) {
  unsigned u = ((unsigned)(unsigned short)s) << 16;
  return __builtin_bit_cast(float, u);
}

// packed f32x2 -> bf16x2 via HIP intrinsic (compiler emits v_cvt_pk_bf16_f32)
__device__ __forceinline__ unsigned pkrn(float a, float b) {
  BF2 r;
  r.h = __float22bfloat162_rn(float2{a, b});
  return r.u;
}

__device__ __forceinline__ float max3f(float a, float b, float c) {
  return fmaxf(fmaxf(a, b), c);
}

// v_permlane32_swap builtin: returns {a', b'} with a' = {a.row0, b.row0},
// b' = {a.row1, b.row1} (rows = lane halves 0-31 / 32-63).
__device__ __forceinline__ void plswap2(unsigned& a, unsigned& b) {
  auto r = __builtin_amdgcn_permlane32_swap((int)a, (int)b, false, false);
  a = (unsigned)r[0];
  b = (unsigned)r[1];
}

// cross-half reduce helpers (replace ds_bpermute shfl with VALU permlane)
__device__ __forceinline__ float xhalf_max(float v) {
  unsigned a = __builtin_bit_cast(unsigned, v), b = a;
  plswap2(a, b);
  return fmaxf(__builtin_bit_cast(float, a), __builtin_bit_cast(float, b));
}
__device__ __forceinline__ float xhalf_sum(float v) {
  unsigned a = __builtin_bit_cast(unsigned, v), b = a;
  plswap2(a, b);
  return __builtin_bit_cast(float, a) + __builtin_bit_cast(float, b);
}

__device__ __forceinline__ short8 cvt8(const float* p) {
  float4 a = *reinterpret_cast<const float4*>(p);
  float4 b2 = *reinterpret_cast<const float4*>(p + 4);
  short8 r;
  r[0] = f2bf(a.x); r[1] = f2bf(a.y); r[2] = f2bf(a.z); r[3] = f2bf(a.w);
  r[4] = f2bf(b2.x); r[5] = f2bf(b2.y); r[6] = f2bf(b2.z); r[7] = f2bf(b2.w);
  return r;
}

__device__ __forceinline__ void gl_lds16(const void* g, void* l) {
  __builtin_amdgcn_global_load_lds(
      (const __attribute__((address_space(1))) void*)g,
      (__attribute__((address_space(3))) void*)l, 16, 0, 0);
}

// ---------------------------------------------------------------------------
// Fused prep: weight transpose+convert AND x/prev bf16 conversion in ONE
// launch (flat 1D grid; id<4096 -> transpose blocks, else cvt blocks).
// ---------------------------------------------------------------------------
__global__ __launch_bounds__(256) void k_prep(
    const float* __restrict__ Wq, const float* __restrict__ Wk,
    const float* __restrict__ Wv, const float* __restrict__ Wo,
    const float* __restrict__ x, const float* __restrict__ prev,
    const int* __restrict__ mask,
    short* __restrict__ WqT, short* __restrict__ WkT,
    short* __restrict__ WvT, short* __restrict__ WoT,
    short* __restrict__ xbf, short* __restrict__ pbf) {
  int id = blockIdx.x;
  if (id < 4096) {
    // weight transpose: id -> (nx, ky, z)
    __shared__ float tile[32][33];
    int z = id >> 10;
    int n0 = (id & 31) * 32, k0 = ((id >> 5) & 31) * 32;
    const float* W = z == 0 ? Wq : z == 1 ? Wk : z == 2 ? Wv : Wo;
    short* WT = z == 0 ? WqT : z == 1 ? WkT : z == 2 ? WvT : WoT;
    int tx = threadIdx.x & 31, ty = threadIdx.x >> 5;
#pragma unroll
    for (int i = 0; i < 4; ++i) {
      int r = i * 8 + ty;
      tile[r][tx] = W[(size_t)(k0 + r) * D + n0 + tx];
    }
    __syncthreads();
#pragma unroll
    for (int i = 0; i < 4; ++i) {
      int r = i * 8 + ty;
      WT[(size_t)(n0 + r) * D + k0 + tx] = f2bf(tile[tx][r]);
    }
  } else {
    // activation conversion: idc -> (chunk, which, b)
    int idc = id - 4096;
    int b = idc >> 11;
    if (mask[b] == 0) return;
    int which = (idc >> 10) & 1;
    int chunk = idc & 1023;
    const float* src = (which ? prev : x) + (size_t)b * S * D;
    short* dst = (which ? pbf : xbf) + (size_t)b * S * D;
    size_t i = ((size_t)chunk * 256 + threadIdx.x) * 8;
    *reinterpret_cast<short8*>(dst + i) = cvt8(src + i);
  }
}

// ---------------------------------------------------------------------------
// Shared GEMM mainloop, T3 2-phase double-buffer + T2 both-sides swizzle:
// LDS slot s of row r holds data column-group s ^ (r&7) (rule #21: linear
// gload_lds dest, inverse-swizzled GLOBAL source, swizzled read address).
// ---------------------------------------------------------------------------
__device__ __forceinline__ void stage128x64(const short* __restrict__ src,
                                            short* lds, int wave, int lane) {
  int sw = (lane & 7) ^ (lane >> 3);  // pre-swizzled source col-group
#pragma unroll
  for (int c = 0; c < 4; ++c) {
    int r0 = wave * 32 + c * 8;
    gl_lds16(src + (size_t)(r0 + (lane >> 3)) * D + sw * 8,
             lds + r0 * 64);
  }
}

__device__ __forceinline__ void gemm_mainloop(
    const short* __restrict__ A, const short* __restrict__ Bm,
    int m0, int n0, short* ldsA, short* ldsB, f32x4 acc[4][4]) {
  int wave = threadIdx.x >> 6, lane = threadIdx.x & 63;
  int wm = wave >> 1, wn = wave & 1;
  int kg = (lane >> 4) * 8, r = lane & 15;
  int rp = (r & 7) << 3;  // row-parity swizzle term (in shorts)
  const short* Ab = A + (size_t)m0 * D;
  const short* Bb = Bm + (size_t)n0 * D;
  // prologue: stage tile 0 into buffer 0
  stage128x64(Ab, ldsA, wave, lane);
  stage128x64(Bb, ldsB, wave, lane);
  __syncthreads();
  int cur = 0;
  for (int kt = 0; kt < D; kt += 64) {
    // issue next tile's loads into the alternate buffer (overlaps MFMA below)
    if (kt + 64 < D) {
      stage128x64(Ab + kt + 64, ldsA + (cur ^ 1) * 8192, wave, lane);
      stage128x64(Bb + kt + 64, ldsB + (cur ^ 1) * 8192, wave, lane);
    }
    const short* lA = ldsA + cur * 8192;
    const short* lB = ldsB + cur * 8192;
#pragma unroll
    for (int kk = 0; kk < 64; kk += 32) {
      int col = (kk + kg) ^ rp;  // swizzled column offset (16B-granular)
      short8 af[4], bf[4];
#pragma unroll
      for (int mt = 0; mt < 4; ++mt)
        af[mt] = *reinterpret_cast<const short8*>(
            lA + (wm * 64 + mt * 16 + r) * 64 + col);
#pragma unroll
      for (int nt = 0; nt < 4; ++nt)
        bf[nt] = *reinterpret_cast<const short8*>(
            lB + (wn * 64 + nt * 16 + r) * 64 + col);
#pragma unroll
      for (int mt = 0; mt < 4; ++mt)
#pragma unroll
        for (int nt = 0; nt < 4; ++nt)
          acc[mt][nt] = __builtin_amdgcn_mfma_f32_16x16x32_bf16(
              af[mt], bf[nt], acc[mt][nt], 0, 0, 0);
    }
    __syncthreads();  // drains prefetch vmcnt + all waves' lds reads
    cur ^= 1;
  }
}

// ---------------------------------------------------------------------------
// Q/K/V projection GEMM. grid (D/128, S/128, 3B), block 256.
// Q head-blocked [b][h][s][64], pre-scaled by 0.125*log2(e).
// K fragment-major K4[b][h][t][ds][lane][8]: coalesced 1KB wave loads in attn.
// V fragment-major V3[b][h][s/16][dv][16]: coalesced 1KB wave loads in attn.
// ---------------------------------------------------------------------------
__global__ __launch_bounds__(256) void k_proj_gemm(
    const short* __restrict__ xbf, const short* __restrict__ pbf,
    const short* __restrict__ WqT, const short* __restrict__ WkT,
    const short* __restrict__ WvT,
    const float* __restrict__ bq, const float* __restrict__ bk,
    const float* __restrict__ bv,
    const int* __restrict__ mask,
    short* __restrict__ Qhb, short* __restrict__ K4, short* __restrict__ V3) {
  int b = blockIdx.z / 3, p = blockIdx.z % 3;
  if (mask[b] == 0) return;
  __shared__ short ldsA[2 * 128 * 64], ldsB[2 * 128 * 64];
  const short* A = (p == 0 ? xbf : pbf) + (size_t)b * S * D;
  const short* WT = p == 0 ? WqT : (p == 1 ? WkT : WvT);
  const float* bias = p == 0 ? bq : (p == 1 ? bk : bv);
  int m0 = blockIdx.y * 128, n0 = blockIdx.x * 128;
  f32x4 acc[4][4] = {};
  gemm_mainloop(A, WT, m0, n0, ldsA, ldsB, acc);

  int wave = threadIdx.x >> 6, lane = threadIdx.x & 63;
  int wm = wave >> 1, wn = wave & 1, r = lane & 15;
  int rbase0 = m0 + wm * 64 + (lane >> 4) * 4;
  if (p == 0) {
    float scale = 0.18033688f;  // 0.125 * log2(e)
#pragma unroll
    for (int mt = 0; mt < 4; ++mt) {
      int rbase = rbase0 + mt * 16;
#pragma unroll
      for (int nt = 0; nt < 4; ++nt) {
        int col = n0 + wn * 64 + nt * 16 + r;
        float bb = bias[col];
        int h = col >> 6, d = col & 63;
#pragma unroll
        for (int j = 0; j < 4; ++j)
          Qhb[((size_t)(b * H + h) * S + rbase + j) * DH + d] =
              f2bf((acc[mt][nt][j] + bb) * scale);
      }
    }
  } else if (p == 1) {
#pragma unroll
    for (int mt = 0; mt < 4; ++mt) {
      int rbase = rbase0 + mt * 16;
#pragma unroll
      for (int nt = 0; nt < 4; ++nt) {
        int col = n0 + wn * 64 + nt * 16 + r;
        float bb = bias[col];
        int h = col >> 6, d = col & 63;
        int ds = d >> 4, hi2 = (d >> 3) & 1, jj = d & 7;
#pragma unroll
        for (int j = 0; j < 4; ++j) {
          int s = rbase + j;
          int t = s >> 5, lr2 = s & 31;
          K4[((((size_t)(b * H + h) * NT + t) * 4 + ds) * 64 +
              hi2 * 32 + lr2) * 8 + jj] = f2bf(acc[mt][nt][j] + bb);
        }
      }
    }
  } else {
#pragma unroll
    for (int mt = 0; mt < 4; ++mt) {
      int rbase = rbase0 + mt * 16;
#pragma unroll
      for (int nt = 0; nt < 4; ++nt) {
        int col = n0 + wn * 64 + nt * 16 + r;
        float bb = bias[col];
        int h = col >> 6, d = col & 63;
        unsigned w0 = pkrn(acc[mt][nt][0] + bb, acc[mt][nt][1] + bb);
        unsigned w1 = pkrn(acc[mt][nt][2] + bb, acc[mt][nt][3] + bb);
        // V3 offset: ((bh*(S/16) + s/16)*64 + d)*16 + (s&15); 4 consecutive s
        size_t off = (((size_t)(b * H + h) * (S / 16) + (rbase >> 4)) * 64 + d)
                         * 16 + (rbase & 15);
        *reinterpret_cast<uint2v*>(V3 + off) = (uint2v){w0, w1};
      }
    }
  }
}

// ---------------------------------------------------------------------------
// Per-kv-tile max K-row norm from K4: Knrm[bh*NT+t] = max_{row in tile} |K_row|.
// grid (NT, H, B), block 64 (one wave per tile).
// ---------------------------------------------------------------------------
__global__ __launch_bounds__(64) void k_knorm(
    const short* __restrict__ K4, const int* __restrict__ mask,
    float* __restrict__ Knrm) {
  int b = blockIdx.z;
  if (mask[b] == 0) return;
  int h = blockIdx.y, t = blockIdx.x;
  int lane = threadIdx.x;
  const short* kp = K4 + ((size_t)(b * H + h) * NT + t) * 2048 + lane * 8;
  float s = 0.f;
#pragma unroll
  for (int ds = 0; ds < 4; ++ds) {
    short8 v = *reinterpret_cast<const short8*>(kp + ds * 512);
#pragma unroll
    for (int j = 0; j < 8; ++j) {
      float f = bf2f(v[j]);
      s += f * f;
    }
  }
  s += __shfl_xor(s, 32);  // combine the two d-halves of the row
#pragma unroll
  for (int off = 2; off < 64; off <<= 1) s = fmaxf(s, __shfl_xor(s, off));
  s = fmaxf(s, __shfl_xor(s, 1));
  if (lane == 0) Knrm[(size_t)(b * H + h) * NT + t] = __builtin_sqrtf(s);
}

// ---------------------------------------------------------------------------
// Output projection + bias + residual (active) / copy (inactive).
// ---------------------------------------------------------------------------
__global__ __launch_bounds__(256) void k_out_gemm(
    const float* __restrict__ x, const short* __restrict__ attn,
    const short* __restrict__ WoT, const float* __restrict__ bo,
    const int* __restrict__ mask, float* __restrict__ out) {
  int b = blockIdx.z;
  int m0 = blockIdx.y * 128, n0 = blockIdx.x * 128;
  if (mask[b] == 0) {
#pragma unroll
    for (int i = 0; i < 16; ++i) {
      int f = threadIdx.x + i * 256;
      int row = f >> 5, cc = (f & 31) << 2;
      size_t idx = ((size_t)(b * S + m0 + row)) * D + n0 + cc;
      *reinterpret_cast<float4*>(out + idx) =
          *reinterpret_cast<const float4*>(x + idx);
    }
    return;
  }
  __shared__ short ldsA[2 * 128 * 64], ldsB[2 * 128 * 64];
  const short* A = attn + (size_t)b * S * D;
  f32x4 acc[4][4] = {};
  gemm_mainloop(A, WoT, m0, n0, ldsA, ldsB, acc);

  int wave = threadIdx.x >> 6, lane = threadIdx.x & 63;
  int wm = wave >> 1, wn = wave & 1, r = lane & 15;
  int rbase0 = m0 + wm * 64 + (lane >> 4) * 4;
#pragma unroll
  for (int mt = 0; mt < 4; ++mt) {
    int rbase = rbase0 + mt * 16;
#pragma unroll
    for (int nt = 0; nt < 4; ++nt) {
      int col = n0 + wn * 64 + nt * 16 + r;
      float bb = bo[col];
#pragma unroll
      for (int j = 0; j < 4; ++j) {
        size_t idx = (size_t)(b * S + rbase + j) * D + col;
        out[idx] = x[idx] + acc[mt][nt][j] + bb;
      }
    }
  }
}

// ---------------------------------------------------------------------------
// Flash attention, fixed-reference softmax, pair sweep with V-LOAD HOISTING
// (V fragments issue BEFORE the QK^T chain so V latency hides under softmax;
// previously V loads issued post-pack, exposing ~300cy before PV) and T5
// s_setprio(1) around MFMA clusters (independent barrier-free waves = the
// m191-validated setprio regime). kv-split (t&3), sound tile-skip,
// fragment-major K4/V3, permlane cross-lane, LPT head order.
// grid (S/32, H, B).
// ---------------------------------------------------------------------------
__global__ __launch_bounds__(256) void k_attn(
    const short* __restrict__ Qhb, const short* __restrict__ K4,
    const short* __restrict__ V3, const float* __restrict__ Knrm,
    const int* __restrict__ mask, short* __restrict__ attn) {
  int b = blockIdx.z;
  if (mask[b] == 0) return;
  int h = (H - 1) - blockIdx.y;  // LPT: heavy heads (high h) first
  int wave = threadIdx.x >> 6, lane = threadIdx.x & 63;
  int lr = lane & 31, hi = lane >> 5;
  int q0 = blockIdx.x * 32;
  float slope2 = exp2f(-0.5f * (float)(h + 1)) * 1.44269504f;
  int td = q0 >> 5;

  size_t bh = (size_t)(b * H + h);
  const short* Qb = Qhb + bh * S * DH;
  const short* Kb = K4 + bh * NT * 2048;
  const short* Vb = V3 + bh * (S / 16) * 1024;

  __shared__ alignas(16) short po[4][32][68];
  __shared__ float mlm[4][32], mll[4][32];
  __shared__ float mrow_s[32];
  __shared__ float mmin_s;

  // per-lane k'rel offsets (k'rel = (r2&3) + 8*(r2>>2) + 4*hi), minus lr
  f32x16 off16;
#pragma unroll
  for (int r2 = 0; r2 < 16; ++r2)
    off16[r2] = (float)((r2 & 3) + 8 * (r2 >> 2) + 4 * hi - lr);

  // hoist Q B-fragments (col = q = lane&31, depth d = ds*16 + hi*8 + j)
  short8 qf[4];
  const short* qp = Qb + (size_t)(q0 + lr) * DH + hi * 8;
#pragma unroll
  for (int ds = 0; ds < 4; ++ds)
    qf[ds] = *reinterpret_cast<const short8*>(qp + ds * 16);

  // wave-max |Qs| (same q rows for all waves)
  float qn2 = 0.f;
#pragma unroll
  for (int ds = 0; ds < 4; ++ds)
#pragma unroll
    for (int j = 0; j < 8; ++j) {
      float f = bf2f(qf[ds][j]);
      qn2 += f * f;
    }
  qn2 += __shfl_xor(qn2, 32);
#pragma unroll
  for (int off = 1; off < 32; off <<= 1)
    qn2 = fmaxf(qn2, __shfl_xor(qn2, off));
  float qn = __builtin_sqrtf(qn2);

  // lane t holds tile t's max K-row norm (NT == 64 == wavesize)
  float kn = Knrm[bh * NT + lane];

  f32x16 o0 = {}, o1 = {};
  float m = 0.f, l = 0.f;

  struct Vregs { short8 a0, b0, a1, b1; };
  auto loadV = [&](int t) {
    const short* vp = Vb + (size_t)(t * 2) * 1024 + lr * 16 + hi * 8;
    Vregs v;
    v.a0 = *reinterpret_cast<const short8*>(vp);
    v.b0 = *reinterpret_cast<const short8*>(vp + 512);
    v.a1 = *reinterpret_cast<const short8*>(vp + 1024);
    v.b1 = *reinterpret_cast<const short8*>(vp + 1536);
    return v;
  };

  // pack P (in c, any positive scale) -> PV B-fragments and accumulate PV
  auto pv = [&](f32x16& c, const Vregs& v) {
    unsigned c0 = pkrn(c[0], c[1]), c1 = pkrn(c[2], c[3]);
    unsigned c2 = pkrn(c[4], c[5]), c3 = pkrn(c[6], c[7]);
    unsigned c4 = pkrn(c[8], c[9]), c5 = pkrn(c[10], c[11]);
    unsigned c6 = pkrn(c[12], c[13]), c7 = pkrn(c[14], c[15]);
    plswap2(c0, c2);
    plswap2(c1, c3);
    plswap2(c4, c6);
    plswap2(c5, c7);
    U8 pb0, pb1;
    pb0.u[0] = c0; pb0.u[1] = c1; pb0.u[2] = c2; pb0.u[3] = c3;
    pb1.u[0] = c4; pb1.u[1] = c5; pb1.u[2] = c6; pb1.u[3] = c7;
    __builtin_amdgcn_s_setprio(1);
    o0 = __builtin_amdgcn_mfma_f32_32x32x16_bf16(v.a0, pb0.s, o0, 0, 0, 0);
    o1 = __builtin_amdgcn_mfma_f32_32x32x16_bf16(v.b0, pb0.s, o1, 0, 0, 0);
    o0 = __builtin_amdgcn_mfma_f32_32x32x16_bf16(v.a1, pb1.s, o0, 0, 0, 0);
    o1 = __builtin_amdgcn_mfma_f32_32x32x16_bf16(v.b1, pb1.s, o1, 0, 0, 0);
    __builtin_amdgcn_s_setprio(0);
  };

  auto qkt = [&](int t) {
    const short* kp = Kb + (size_t)t * 2048 + lane * 8;
    short8 k0 = *reinterpret_cast<const short8*>(kp);
    short8 k1 = *reinterpret_cast<const short8*>(kp + 512);
    short8 k2 = *reinterpret_cast<const short8*>(kp + 1024);
    short8 k3 = *reinterpret_cast<const short8*>(kp + 1536);
    f32x16 c = {};
    __builtin_amdgcn_s_setprio(1);
    c = __builtin_amdgcn_mfma_f32_32x32x16_bf16(k0, qf[0], c, 0, 0, 0);
    c = __builtin_amdgcn_mfma_f32_32x32x16_bf16(k1, qf[1], c, 0, 0, 0);
    c = __builtin_amdgcn_mfma_f32_32x32x16_bf16(k2, qf[2], c, 0, 0, 0);
    c = __builtin_amdgcn_mfma_f32_32x32x16_bf16(k3, qf[3], c, 0, 0, 0);
    __builtin_amdgcn_s_setprio(0);
    return c;
  };

  auto expsum = [&](f32x16& c) {
#pragma unroll
    for (int r2 = 0; r2 < 16; ++r2) c[r2] = __builtin_exp2f(c[r2]);
    float sa = (c[0] + c[1]) + (c[2] + c[3]);
    float sb = (c[4] + c[5]) + (c[6] + c[7]);
    float sc2 = (c[8] + c[9]) + (c[10] + c[11]);
    float sd = (c[12] + c[13]) + (c[14] + c[15]);
    return (sa + sb) + (sc2 + sd);
  };

  // 1) diagonal tile: owner wave computes per-row m, publishes via LDS
  int wd = td & 3;
  if (wave == wd) {
    Vregs vd = loadV(td);
    f32x16 c = qkt(td);
    f32x16 dd = off16 + (float)(td * 32 - q0);
#pragma unroll
    for (int r2 = 0; r2 < 16; ++r2)
      c[r2] = __builtin_fmaf(-slope2, __builtin_fabsf(dd[r2]), c[r2]);
    float tmax = fmaxf(
        max3f(max3f(c[0], c[1], c[2]), max3f(c[3], c[4], c[5]),
              max3f(c[6], c[7], c[8])),
        max3f(max3f(c[9], c[10], c[11]), max3f(c[12], c[13], c[14]), c[15]));
    m = xhalf_max(tmax);
    c -= m;
    l = xhalf_sum(expsum(c));
    pv(c, vd);
    if (hi == 0) mrow_s[lr] = m;
    float mm = m;
#pragma unroll
    for (int off = 1; off < 32; off <<= 1)
      mm = fminf(mm, __shfl_xor(mm, off));
    if (lane == 0) mmin_s = mm;
  }
  __syncthreads();
  float mmin = mmin_s;
  m = mrow_s[lr];  // all waves share the fixed per-row reference

  // 2) 64-bit keep mask: lane t evaluates tile t (sound C-S + alibi bound);
  //    interleaved distribution: wave w sweeps tiles {t : t&3 == w}
  int dlow = q0 - (lane * 32 + 31), dhigh = lane * 32 - (q0 + 31);
  float dmin = (float)max(0, max(dlow, dhigh));
  bool keepc = (__builtin_fmaf(-slope2, dmin, qn * kn) >= mmin - 36.0f);
  unsigned long long keep = __ballot(keepc) & ~(1ull << td);
  keep &= (0x1111111111111111ull << wave);

  // 3) sweep kept tiles in independent pairs; V loads issue FIRST so their
  //    latency hides under the QK^T chain + softmax VALU.
  while (keep) {
    int t0 = __builtin_ctzll(keep);
    keep &= keep - 1;
    if (keep) {
      int t1 = __builtin_ctzll(keep);
      keep &= keep - 1;
      Vregs v0 = loadV(t0);
      Vregs v1 = loadV(t1);
      f32x16 c0 = qkt(t0);
      f32x16 c1 = qkt(t1);
      float ss0 = (t0 > td) ? -slope2 : slope2;
      float ss1 = (t1 > td) ? -slope2 : slope2;
      float sb0 = __builtin_fmaf(ss0, (float)(t0 * 32 - q0), -m);
      float sb1 = __builtin_fmaf(ss1, (float)(t1 * 32 - q0), -m);
      c0 += sb0;
      c0 += ss0 * off16;
      c1 += sb1;
      c1 += ss1 * off16;
      float s0 = expsum(c0);
      float s1 = expsum(c1);
      l += xhalf_sum(s0 + s1);
      pv(c0, v0);
      pv(c1, v1);
    } else {
      Vregs v0 = loadV(t0);
      f32x16 c = qkt(t0);
      float ss = (t0 > td) ? -slope2 : slope2;
      float sb = __builtin_fmaf(ss, (float)(t0 * 32 - q0), -m);
      c += sb;
      c += ss * off16;
      l += xhalf_sum(expsum(c));
      pv(c, v0);
    }
  }

  // 4) write per-wave partials (dv = 8g + 4hi + j; o1 -> dv+32)
#pragma unroll
  for (int g = 0; g < 4; ++g) {
    unsigned w0 = pkrn(o0[g * 4 + 0], o0[g * 4 + 1]);
    unsigned w1 = pkrn(o0[g * 4 + 2], o0[g * 4 + 3]);
    unsigned w2 = pkrn(o1[g * 4 + 0], o1[g * 4 + 1]);
    unsigned w3 = pkrn(o1[g * 4 + 2], o1[g * 4 + 3]);
    *reinterpret_cast<uint2v*>(&po[wave][lr][8 * g + 4 * hi]) = (uint2v){w0, w1};
    *reinterpret_cast<uint2v*>(&po[wave][lr][32 + 8 * g + 4 * hi]) =
        (uint2v){w2, w3};
  }
  if (hi == 0) { mlm[wave][lr] = m; mll[wave][lr] = l; }
  __syncthreads();

  // 5) flash combine across the 4 waves (all m equal -> sc == 1, exact)
  int qr = threadIdx.x & 31, cc = threadIdx.x >> 5;  // cc = dv chunk (0..7)
  float mw[4], M = -INFINITY;
#pragma unroll
  for (int w = 0; w < 4; ++w) { mw[w] = mlm[w][qr]; M = fmaxf(M, mw[w]); }
  float L = 0.f, O[8] = {};
#pragma unroll
  for (int w = 0; w < 4; ++w) {
    float sc = __builtin_exp2f(mw[w] - M);
    L += sc * mll[w][qr];
    short4v a = *reinterpret_cast<const short4v*>(&po[w][qr][cc * 8]);
    short4v b2 = *reinterpret_cast<const short4v*>(&po[w][qr][cc * 8 + 4]);
#pragma unroll
    for (int j = 0; j < 4; ++j) {
      O[j] += sc * bf2f(a[j]);
      O[4 + j] += sc * bf2f(b2[j]);
    }
  }
  float invL = 1.0f / L;
  U8 r8;
  r8.u[0] = pkrn(O[0] * invL, O[1] * invL);
  r8.u[1] = pkrn(O[2] * invL, O[3] * invL);
  r8.u[2] = pkrn(O[4] * invL, O[5] * invL);
  r8.u[3] = pkrn(O[6] * invL, O[7] * invL);
  *reinterpret_cast<short8*>(
      attn + (size_t)(b * S + q0 + qr) * D + h * DH + cc * 8) = r8.s;
}

}  // namespace

extern "C" void kernel_launch(void* const* d_in, const int* in_sizes, int n_in,
                              void* d_out, int out_size, void* d_ws, size_t ws_size,
                              hipStream_t stream) {
  const float* x    = (const float*)d_in[0];
  const float* prev = (const float*)d_in[1];
  const float* Wq   = (const float*)d_in[2];
  const float* Wk   = (const float*)d_in[3];
  const float* Wv   = (const float*)d_in[4];
  const float* Wo   = (const float*)d_in[5];
  const float* bq   = (const float*)d_in[6];
  const float* bk   = (const float*)d_in[7];
  const float* bv   = (const float*)d_in[8];
  const float* bo   = (const float*)d_in[9];
  const int* mask   = (const int*)d_in[10];
  float* out = (float*)d_out;
  char* ws = (char*)d_ws;

  constexpr size_t WSZ = (size_t)D * D * 2;      // 2 MB per bf16 weight
  constexpr size_t ASZ = (size_t)B * S * D * 2;  // 16 MB per bf16 activation
  short* WqT  = (short*)(ws);
  short* WkT  = (short*)(ws + WSZ);
  short* WvT  = (short*)(ws + 2 * WSZ);
  short* WoT  = (short*)(ws + 3 * WSZ);
  short* Qhb  = (short*)(ws + 4 * WSZ);
  short* K4   = (short*)(ws + 4 * WSZ + ASZ);
  short* V3   = (short*)(ws + 4 * WSZ + 2 * ASZ);
  short* xbf  = (short*)(ws + 4 * WSZ + 3 * ASZ);  // attn aliases xbf (dead after proj)
  short* pbf  = (short*)(ws + 4 * WSZ + 4 * ASZ);
  float* Knrm = (float*)(ws + 4 * WSZ + 5 * ASZ);  // B*H*NT floats (16 KB)
  short* attn = xbf;

  k_prep<<<dim3(4096 + 8192), 256, 0, stream>>>(
      Wq, Wk, Wv, Wo, x, prev, mask, WqT, WkT, WvT, WoT, xbf, pbf);
  k_proj_gemm<<<dim3(D / 128, S / 128, 3 * B), 256, 0, stream>>>(
      xbf, pbf, WqT, WkT, WvT, bq, bk, bv, mask, Qhb, K4, V3);
  k_knorm<<<dim3(NT, H, B), 64, 0, stream>>>(K4, mask, Knrm);
  k_attn<<<dim3(S / 32, H, B), 256, 0, stream>>>(
      Qhb, K4, V3, Knrm, mask, attn);
  k_out_gemm<<<dim3(D / 128, S / 128, B), 256, 0, stream>>>(
      x, attn, WoT, bo, mask, out);
}

// Round 21
// 136.779 us; speedup vs baseline: 1.0578x; 1.0578x over previous
//
#include <hip/hip_runtime.h>
#include <hip/hip_bf16.h>

namespace {

constexpr int B = 4, S = 2048, D = 1024, H = 16, DH = 64;
constexpr int NT = S / 32;  // 64 kv tiles

typedef __attribute__((ext_vector_type(8))) short short8;
typedef __attribute__((ext_vector_type(4))) short short4v;
typedef __attribute__((ext_vector_type(2))) unsigned uint2v;
typedef __attribute__((ext_vector_type(4))) float f32x4;
typedef __attribute__((ext_vector_type(16))) float f32x16;

union U8 { unsigned u[4]; short8 s; };
union BF2 { __hip_bfloat162 h; unsigned u; };

__device__ __forceinline__ short f2bf(float f) {
  unsigned u = __builtin_bit_cast(unsigned, f);
  u = (u + 0x7fffu + ((u >> 16) & 1u)) >> 16;
  return (short)u;
}

__device__ __forceinline__ float bf2f(short s) {
  unsigned u = ((unsigned)(unsigned short)s) << 16;
  return __builtin_bit_cast(float, u);
}

// packed f32x2 -> bf16x2 via HIP intrinsic (compiler emits v_cvt_pk_bf16_f32)
__device__ __forceinline__ unsigned pkrn(float a, float b) {
  BF2 r;
  r.h = __float22bfloat162_rn(float2{a, b});
  return r.u;
}

__device__ __forceinline__ float max3f(float a, float b, float c) {
  return fmaxf(fmaxf(a, b), c);
}

// v_permlane32_swap builtin: returns {a', b'} with a' = {a.row0, b.row0},
// b' = {a.row1, b.row1} (rows = lane halves 0-31 / 32-63).
__device__ __forceinline__ void plswap2(unsigned& a, unsigned& b) {
  auto r = __builtin_amdgcn_permlane32_swap((int)a, (int)b, false, false);
  a = (unsigned)r[0];
  b = (unsigned)r[1];
}

// cross-half reduce helpers (replace ds_bpermute shfl with VALU permlane)
__device__ __forceinline__ float xhalf_max(float v) {
  unsigned a = __builtin_bit_cast(unsigned, v), b = a;
  plswap2(a, b);
  return fmaxf(__builtin_bit_cast(float, a), __builtin_bit_cast(float, b));
}
__device__ __forceinline__ float xhalf_sum(float v) {
  unsigned a = __builtin_bit_cast(unsigned, v), b = a;
  plswap2(a, b);
  return __builtin_bit_cast(float, a) + __builtin_bit_cast(float, b);
}

__device__ __forceinline__ short8 cvt8(const float* p) {
  float4 a = *reinterpret_cast<const float4*>(p);
  float4 b2 = *reinterpret_cast<const float4*>(p + 4);
  short8 r;
  r[0] = f2bf(a.x); r[1] = f2bf(a.y); r[2] = f2bf(a.z); r[3] = f2bf(a.w);
  r[4] = f2bf(b2.x); r[5] = f2bf(b2.y); r[6] = f2bf(b2.z); r[7] = f2bf(b2.w);
  return r;
}

__device__ __forceinline__ void gl_lds16(const void* g, void* l) {
  __builtin_amdgcn_global_load_lds(
      (const __attribute__((address_space(1))) void*)g,
      (__attribute__((address_space(3))) void*)l, 16, 0, 0);
}

// ---------------------------------------------------------------------------
// Fused prep: weight transpose+convert AND x/prev bf16 conversion in ONE
// launch (flat 1D grid; id<4096 -> transpose blocks, else cvt blocks).
// ---------------------------------------------------------------------------
__global__ __launch_bounds__(256) void k_prep(
    const float* __restrict__ Wq, const float* __restrict__ Wk,
    const float* __restrict__ Wv, const float* __restrict__ Wo,
    const float* __restrict__ x, const float* __restrict__ prev,
    const int* __restrict__ mask,
    short* __restrict__ WqT, short* __restrict__ WkT,
    short* __restrict__ WvT, short* __restrict__ WoT,
    short* __restrict__ xbf, short* __restrict__ pbf) {
  int id = blockIdx.x;
  if (id < 4096) {
    // weight transpose: id -> (nx, ky, z)
    __shared__ float tile[32][33];
    int z = id >> 10;
    int n0 = (id & 31) * 32, k0 = ((id >> 5) & 31) * 32;
    const float* W = z == 0 ? Wq : z == 1 ? Wk : z == 2 ? Wv : Wo;
    short* WT = z == 0 ? WqT : z == 1 ? WkT : z == 2 ? WvT : WoT;
    int tx = threadIdx.x & 31, ty = threadIdx.x >> 5;
#pragma unroll
    for (int i = 0; i < 4; ++i) {
      int r = i * 8 + ty;
      tile[r][tx] = W[(size_t)(k0 + r) * D + n0 + tx];
    }
    __syncthreads();
#pragma unroll
    for (int i = 0; i < 4; ++i) {
      int r = i * 8 + ty;
      WT[(size_t)(n0 + r) * D + k0 + tx] = f2bf(tile[tx][r]);
    }
  } else {
    // activation conversion: idc -> (chunk, which, b)
    int idc = id - 4096;
    int b = idc >> 11;
    if (mask[b] == 0) return;
    int which = (idc >> 10) & 1;
    int chunk = idc & 1023;
    const float* src = (which ? prev : x) + (size_t)b * S * D;
    short* dst = (which ? pbf : xbf) + (size_t)b * S * D;
    size_t i = ((size_t)chunk * 256 + threadIdx.x) * 8;
    *reinterpret_cast<short8*>(dst + i) = cvt8(src + i);
  }
}

// ---------------------------------------------------------------------------
// Shared GEMM mainloop, T3 2-phase double-buffer + T2 both-sides swizzle:
// LDS slot s of row r holds data column-group s ^ (r&7) (rule #21: linear
// gload_lds dest, inverse-swizzled GLOBAL source, swizzled read address).
// ---------------------------------------------------------------------------
__device__ __forceinline__ void stage128x64(const short* __restrict__ src,
                                            short* lds, int wave, int lane) {
  int sw = (lane & 7) ^ (lane >> 3);  // pre-swizzled source col-group
#pragma unroll
  for (int c = 0; c < 4; ++c) {
    int r0 = wave * 32 + c * 8;
    gl_lds16(src + (size_t)(r0 + (lane >> 3)) * D + sw * 8,
             lds + r0 * 64);
  }
}

__device__ __forceinline__ void gemm_mainloop(
    const short* __restrict__ A, const short* __restrict__ Bm,
    int m0, int n0, short* ldsA, short* ldsB, f32x4 acc[4][4]) {
  int wave = threadIdx.x >> 6, lane = threadIdx.x & 63;
  int wm = wave >> 1, wn = wave & 1;
  int kg = (lane >> 4) * 8, r = lane & 15;
  int rp = (r & 7) << 3;  // row-parity swizzle term (in shorts)
  const short* Ab = A + (size_t)m0 * D;
  const short* Bb = Bm + (size_t)n0 * D;
  // prologue: stage tile 0 into buffer 0
  stage128x64(Ab, ldsA, wave, lane);
  stage128x64(Bb, ldsB, wave, lane);
  __syncthreads();
  int cur = 0;
  for (int kt = 0; kt < D; kt += 64) {
    // issue next tile's loads into the alternate buffer (overlaps MFMA below)
    if (kt + 64 < D) {
      stage128x64(Ab + kt + 64, ldsA + (cur ^ 1) * 8192, wave, lane);
      stage128x64(Bb + kt + 64, ldsB + (cur ^ 1) * 8192, wave, lane);
    }
    const short* lA = ldsA + cur * 8192;
    const short* lB = ldsB + cur * 8192;
#pragma unroll
    for (int kk = 0; kk < 64; kk += 32) {
      int col = (kk + kg) ^ rp;  // swizzled column offset (16B-granular)
      short8 af[4], bf[4];
#pragma unroll
      for (int mt = 0; mt < 4; ++mt)
        af[mt] = *reinterpret_cast<const short8*>(
            lA + (wm * 64 + mt * 16 + r) * 64 + col);
#pragma unroll
      for (int nt = 0; nt < 4; ++nt)
        bf[nt] = *reinterpret_cast<const short8*>(
            lB + (wn * 64 + nt * 16 + r) * 64 + col);
#pragma unroll
      for (int mt = 0; mt < 4; ++mt)
#pragma unroll
        for (int nt = 0; nt < 4; ++nt)
          acc[mt][nt] = __builtin_amdgcn_mfma_f32_16x16x32_bf16(
              af[mt], bf[nt], acc[mt][nt], 0, 0, 0);
    }
    __syncthreads();  // drains prefetch vmcnt + all waves' lds reads
    cur ^= 1;
  }
}

// ---------------------------------------------------------------------------
// Q/K/V projection GEMM. grid (D/128, S/128, 3B), block 256.
// Q head-blocked [b][h][s][64], pre-scaled by 0.125*log2(e).
// K fragment-major K4[b][h][t][ds][lane][8]: coalesced 1KB wave loads in attn.
// V fragment-major V3[b][h][s/16][dv][16]: coalesced 1KB wave loads in attn.
// ---------------------------------------------------------------------------
__global__ __launch_bounds__(256) void k_proj_gemm(
    const short* __restrict__ xbf, const short* __restrict__ pbf,
    const short* __restrict__ WqT, const short* __restrict__ WkT,
    const short* __restrict__ WvT,
    const float* __restrict__ bq, const float* __restrict__ bk,
    const float* __restrict__ bv,
    const int* __restrict__ mask,
    short* __restrict__ Qhb, short* __restrict__ K4, short* __restrict__ V3) {
  int b = blockIdx.z / 3, p = blockIdx.z % 3;
  if (mask[b] == 0) return;
  __shared__ short ldsA[2 * 128 * 64], ldsB[2 * 128 * 64];
  const short* A = (p == 0 ? xbf : pbf) + (size_t)b * S * D;
  const short* WT = p == 0 ? WqT : (p == 1 ? WkT : WvT);
  const float* bias = p == 0 ? bq : (p == 1 ? bk : bv);
  int m0 = blockIdx.y * 128, n0 = blockIdx.x * 128;
  f32x4 acc[4][4] = {};
  gemm_mainloop(A, WT, m0, n0, ldsA, ldsB, acc);

  int wave = threadIdx.x >> 6, lane = threadIdx.x & 63;
  int wm = wave >> 1, wn = wave & 1, r = lane & 15;
  int rbase0 = m0 + wm * 64 + (lane >> 4) * 4;
  if (p == 0) {
    float scale = 0.18033688f;  // 0.125 * log2(e)
#pragma unroll
    for (int mt = 0; mt < 4; ++mt) {
      int rbase = rbase0 + mt * 16;
#pragma unroll
      for (int nt = 0; nt < 4; ++nt) {
        int col = n0 + wn * 64 + nt * 16 + r;
        float bb = bias[col];
        int h = col >> 6, d = col & 63;
#pragma unroll
        for (int j = 0; j < 4; ++j)
          Qhb[((size_t)(b * H + h) * S + rbase + j) * DH + d] =
              f2bf((acc[mt][nt][j] + bb) * scale);
      }
    }
  } else if (p == 1) {
#pragma unroll
    for (int mt = 0; mt < 4; ++mt) {
      int rbase = rbase0 + mt * 16;
#pragma unroll
      for (int nt = 0; nt < 4; ++nt) {
        int col = n0 + wn * 64 + nt * 16 + r;
        float bb = bias[col];
        int h = col >> 6, d = col & 63;
        int ds = d >> 4, hi2 = (d >> 3) & 1, jj = d & 7;
#pragma unroll
        for (int j = 0; j < 4; ++j) {
          int s = rbase + j;
          int t = s >> 5, lr2 = s & 31;
          K4[((((size_t)(b * H + h) * NT + t) * 4 + ds) * 64 +
              hi2 * 32 + lr2) * 8 + jj] = f2bf(acc[mt][nt][j] + bb);
        }
      }
    }
  } else {
#pragma unroll
    for (int mt = 0; mt < 4; ++mt) {
      int rbase = rbase0 + mt * 16;
#pragma unroll
      for (int nt = 0; nt < 4; ++nt) {
        int col = n0 + wn * 64 + nt * 16 + r;
        float bb = bias[col];
        int h = col >> 6, d = col & 63;
        unsigned w0 = pkrn(acc[mt][nt][0] + bb, acc[mt][nt][1] + bb);
        unsigned w1 = pkrn(acc[mt][nt][2] + bb, acc[mt][nt][3] + bb);
        // V3 offset: ((bh*(S/16) + s/16)*64 + d)*16 + (s&15); 4 consecutive s
        size_t off = (((size_t)(b * H + h) * (S / 16) + (rbase >> 4)) * 64 + d)
                         * 16 + (rbase & 15);
        *reinterpret_cast<uint2v*>(V3 + off) = (uint2v){w0, w1};
      }
    }
  }
}

// ---------------------------------------------------------------------------
// Per-kv-tile max K-row norm from K4: Knrm[bh*NT+t] = max_{row in tile} |K_row|.
// grid (NT, H, B), block 64 (one wave per tile).
// ---------------------------------------------------------------------------
__global__ __launch_bounds__(64) void k_knorm(
    const short* __restrict__ K4, const int* __restrict__ mask,
    float* __restrict__ Knrm) {
  int b = blockIdx.z;
  if (mask[b] == 0) return;
  int h = blockIdx.y, t = blockIdx.x;
  int lane = threadIdx.x;
  const short* kp = K4 + ((size_t)(b * H + h) * NT + t) * 2048 + lane * 8;
  float s = 0.f;
#pragma unroll
  for (int ds = 0; ds < 4; ++ds) {
    short8 v = *reinterpret_cast<const short8*>(kp + ds * 512);
#pragma unroll
    for (int j = 0; j < 8; ++j) {
      float f = bf2f(v[j]);
      s += f * f;
    }
  }
  s += __shfl_xor(s, 32);  // combine the two d-halves of the row
#pragma unroll
  for (int off = 2; off < 64; off <<= 1) s = fmaxf(s, __shfl_xor(s, off));
  s = fmaxf(s, __shfl_xor(s, 1));
  if (lane == 0) Knrm[(size_t)(b * H + h) * NT + t] = __builtin_sqrtf(s);
}

// ---------------------------------------------------------------------------
// Output projection + bias + residual (active) / copy (inactive).
// ---------------------------------------------------------------------------
__global__ __launch_bounds__(256) void k_out_gemm(
    const float* __restrict__ x, const short* __restrict__ attn,
    const short* __restrict__ WoT, const float* __restrict__ bo,
    const int* __restrict__ mask, float* __restrict__ out) {
  int b = blockIdx.z;
  int m0 = blockIdx.y * 128, n0 = blockIdx.x * 128;
  if (mask[b] == 0) {
#pragma unroll
    for (int i = 0; i < 16; ++i) {
      int f = threadIdx.x + i * 256;
      int row = f >> 5, cc = (f & 31) << 2;
      size_t idx = ((size_t)(b * S + m0 + row)) * D + n0 + cc;
      *reinterpret_cast<float4*>(out + idx) =
          *reinterpret_cast<const float4*>(x + idx);
    }
    return;
  }
  __shared__ short ldsA[2 * 128 * 64], ldsB[2 * 128 * 64];
  const short* A = attn + (size_t)b * S * D;
  f32x4 acc[4][4] = {};
  gemm_mainloop(A, WoT, m0, n0, ldsA, ldsB, acc);

  int wave = threadIdx.x >> 6, lane = threadIdx.x & 63;
  int wm = wave >> 1, wn = wave & 1, r = lane & 15;
  int rbase0 = m0 + wm * 64 + (lane >> 4) * 4;
#pragma unroll
  for (int mt = 0; mt < 4; ++mt) {
    int rbase = rbase0 + mt * 16;
#pragma unroll
    for (int nt = 0; nt < 4; ++nt) {
      int col = n0 + wn * 64 + nt * 16 + r;
      float bb = bo[col];
#pragma unroll
      for (int j = 0; j < 4; ++j) {
        size_t idx = (size_t)(b * S + rbase + j) * D + col;
        out[idx] = x[idx] + acc[mt][nt][j] + bb;
      }
    }
  }
}

// ---------------------------------------------------------------------------
// Flash attention, fixed-reference softmax + independent-pair sweep (R19
// best-known state): no max/rescale in the sweep, paired tiles fully
// decoupled; kv-split (t&3), sound tile-skip, fragment-major K4/V3,
// permlane cross-lane, LPT head order. grid (S/32, H, B).
// ---------------------------------------------------------------------------
__global__ __launch_bounds__(256) void k_attn(
    const short* __restrict__ Qhb, const short* __restrict__ K4,
    const short* __restrict__ V3, const float* __restrict__ Knrm,
    const int* __restrict__ mask, short* __restrict__ attn) {
  int b = blockIdx.z;
  if (mask[b] == 0) return;
  int h = (H - 1) - blockIdx.y;  // LPT: heavy heads (high h) first
  int wave = threadIdx.x >> 6, lane = threadIdx.x & 63;
  int lr = lane & 31, hi = lane >> 5;
  int q0 = blockIdx.x * 32;
  float slope2 = exp2f(-0.5f * (float)(h + 1)) * 1.44269504f;
  int td = q0 >> 5;

  size_t bh = (size_t)(b * H + h);
  const short* Qb = Qhb + bh * S * DH;
  const short* Kb = K4 + bh * NT * 2048;
  const short* Vb = V3 + bh * (S / 16) * 1024;

  __shared__ alignas(16) short po[4][32][68];
  __shared__ float mlm[4][32], mll[4][32];
  __shared__ float mrow_s[32];
  __shared__ float mmin_s;

  // per-lane k'rel offsets (k'rel = (r2&3) + 8*(r2>>2) + 4*hi), minus lr
  f32x16 off16;
#pragma unroll
  for (int r2 = 0; r2 < 16; ++r2)
    off16[r2] = (float)((r2 & 3) + 8 * (r2 >> 2) + 4 * hi - lr);

  // hoist Q B-fragments (col = q = lane&31, depth d = ds*16 + hi*8 + j)
  short8 qf[4];
  const short* qp = Qb + (size_t)(q0 + lr) * DH + hi * 8;
#pragma unroll
  for (int ds = 0; ds < 4; ++ds)
    qf[ds] = *reinterpret_cast<const short8*>(qp + ds * 16);

  // wave-max |Qs| (same q rows for all waves)
  float qn2 = 0.f;
#pragma unroll
  for (int ds = 0; ds < 4; ++ds)
#pragma unroll
    for (int j = 0; j < 8; ++j) {
      float f = bf2f(qf[ds][j]);
      qn2 += f * f;
    }
  qn2 += __shfl_xor(qn2, 32);
#pragma unroll
  for (int off = 1; off < 32; off <<= 1)
    qn2 = fmaxf(qn2, __shfl_xor(qn2, off));
  float qn = __builtin_sqrtf(qn2);

  // lane t holds tile t's max K-row norm (NT == 64 == wavesize)
  float kn = Knrm[bh * NT + lane];

  f32x16 o0 = {}, o1 = {};
  float m = 0.f, l = 0.f;

  // pack P (in c, any positive scale) -> PV B-fragments and accumulate PV
  auto pv = [&](f32x16& c, int t) {
    unsigned c0 = pkrn(c[0], c[1]), c1 = pkrn(c[2], c[3]);
    unsigned c2 = pkrn(c[4], c[5]), c3 = pkrn(c[6], c[7]);
    unsigned c4 = pkrn(c[8], c[9]), c5 = pkrn(c[10], c[11]);
    unsigned c6 = pkrn(c[12], c[13]), c7 = pkrn(c[14], c[15]);
    plswap2(c0, c2);
    plswap2(c1, c3);
    plswap2(c4, c6);
    plswap2(c5, c7);
    U8 pb0, pb1;
    pb0.u[0] = c0; pb0.u[1] = c1; pb0.u[2] = c2; pb0.u[3] = c3;
    pb1.u[0] = c4; pb1.u[1] = c5; pb1.u[2] = c6; pb1.u[3] = c7;
    const short* vp = Vb + (size_t)(t * 2) * 1024 + lr * 16 + hi * 8;
    short8 va0 = *reinterpret_cast<const short8*>(vp);
    short8 vb0 = *reinterpret_cast<const short8*>(vp + 512);
    short8 va1 = *reinterpret_cast<const short8*>(vp + 1024);
    short8 vb1 = *reinterpret_cast<const short8*>(vp + 1536);
    o0 = __builtin_amdgcn_mfma_f32_32x32x16_bf16(va0, pb0.s, o0, 0, 0, 0);
    o1 = __builtin_amdgcn_mfma_f32_32x32x16_bf16(vb0, pb0.s, o1, 0, 0, 0);
    o0 = __builtin_amdgcn_mfma_f32_32x32x16_bf16(va1, pb1.s, o0, 0, 0, 0);
    o1 = __builtin_amdgcn_mfma_f32_32x32x16_bf16(vb1, pb1.s, o1, 0, 0, 0);
  };

  auto qkt = [&](int t) {
    const short* kp = Kb + (size_t)t * 2048 + lane * 8;
    short8 k0 = *reinterpret_cast<const short8*>(kp);
    short8 k1 = *reinterpret_cast<const short8*>(kp + 512);
    short8 k2 = *reinterpret_cast<const short8*>(kp + 1024);
    short8 k3 = *reinterpret_cast<const short8*>(kp + 1536);
    f32x16 c = {};
    c = __builtin_amdgcn_mfma_f32_32x32x16_bf16(k0, qf[0], c, 0, 0, 0);
    c = __builtin_amdgcn_mfma_f32_32x32x16_bf16(k1, qf[1], c, 0, 0, 0);
    c = __builtin_amdgcn_mfma_f32_32x32x16_bf16(k2, qf[2], c, 0, 0, 0);
    c = __builtin_amdgcn_mfma_f32_32x32x16_bf16(k3, qf[3], c, 0, 0, 0);
    return c;
  };

  auto expsum = [&](f32x16& c) {
#pragma unroll
    for (int r2 = 0; r2 < 16; ++r2) c[r2] = __builtin_exp2f(c[r2]);
    float sa = (c[0] + c[1]) + (c[2] + c[3]);
    float sb = (c[4] + c[5]) + (c[6] + c[7]);
    float sc2 = (c[8] + c[9]) + (c[10] + c[11]);
    float sd = (c[12] + c[13]) + (c[14] + c[15]);
    return (sa + sb) + (sc2 + sd);
  };

  // 1) diagonal tile: owner wave computes per-row m, publishes via LDS
  int wd = td & 3;
  if (wave == wd) {
    f32x16 c = qkt(td);
    f32x16 dd = off16 + (float)(td * 32 - q0);
#pragma unroll
    for (int r2 = 0; r2 < 16; ++r2)
      c[r2] = __builtin_fmaf(-slope2, __builtin_fabsf(dd[r2]), c[r2]);
    float tmax = fmaxf(
        max3f(max3f(c[0], c[1], c[2]), max3f(c[3], c[4], c[5]),
              max3f(c[6], c[7], c[8])),
        max3f(max3f(c[9], c[10], c[11]), max3f(c[12], c[13], c[14]), c[15]));
    m = xhalf_max(tmax);
    c -= m;
    l = xhalf_sum(expsum(c));
    pv(c, td);
    if (hi == 0) mrow_s[lr] = m;
    float mm = m;
#pragma unroll
    for (int off = 1; off < 32; off <<= 1)
      mm = fminf(mm, __shfl_xor(mm, off));
    if (lane == 0) mmin_s = mm;
  }
  __syncthreads();
  float mmin = mmin_s;
  m = mrow_s[lr];  // all waves share the fixed per-row reference

  // 2) 64-bit keep mask: lane t evaluates tile t (sound C-S + alibi bound);
  //    interleaved distribution: wave w sweeps tiles {t : t&3 == w}
  int dlow = q0 - (lane * 32 + 31), dhigh = lane * 32 - (q0 + 31);
  float dmin = (float)max(0, max(dlow, dhigh));
  bool keepc = (__builtin_fmaf(-slope2, dmin, qn * kn) >= mmin - 36.0f);
  unsigned long long keep = __ballot(keepc) & ~(1ull << td);
  keep &= (0x1111111111111111ull << wave);

  // 3) sweep kept tiles in INDEPENDENT PAIRS (fixed-reference: no coupling)
  while (keep) {
    int t0 = __builtin_ctzll(keep);
    keep &= keep - 1;
    if (keep) {
      int t1 = __builtin_ctzll(keep);
      keep &= keep - 1;
      f32x16 c0 = qkt(t0);
      f32x16 c1 = qkt(t1);
      float ss0 = (t0 > td) ? -slope2 : slope2;
      float ss1 = (t1 > td) ? -slope2 : slope2;
      float sb0 = __builtin_fmaf(ss0, (float)(t0 * 32 - q0), -m);
      float sb1 = __builtin_fmaf(ss1, (float)(t1 * 32 - q0), -m);
      c0 += sb0;
      c0 += ss0 * off16;
      c1 += sb1;
      c1 += ss1 * off16;
      float s0 = expsum(c0);
      float s1 = expsum(c1);
      l += xhalf_sum(s0 + s1);
      pv(c0, t0);
      pv(c1, t1);
    } else {
      f32x16 c = qkt(t0);
      float ss = (t0 > td) ? -slope2 : slope2;
      float sb = __builtin_fmaf(ss, (float)(t0 * 32 - q0), -m);
      c += sb;
      c += ss * off16;
      l += xhalf_sum(expsum(c));
      pv(c, t0);
    }
  }

  // 4) write per-wave partials (dv = 8g + 4hi + j; o1 -> dv+32)
#pragma unroll
  for (int g = 0; g < 4; ++g) {
    unsigned w0 = pkrn(o0[g * 4 + 0], o0[g * 4 + 1]);
    unsigned w1 = pkrn(o0[g * 4 + 2], o0[g * 4 + 3]);
    unsigned w2 = pkrn(o1[g * 4 + 0], o1[g * 4 + 1]);
    unsigned w3 = pkrn(o1[g * 4 + 2], o1[g * 4 + 3]);
    *reinterpret_cast<uint2v*>(&po[wave][lr][8 * g + 4 * hi]) = (uint2v){w0, w1};
    *reinterpret_cast<uint2v*>(&po[wave][lr][32 + 8 * g + 4 * hi]) =
        (uint2v){w2, w3};
  }
  if (hi == 0) { mlm[wave][lr] = m; mll[wave][lr] = l; }
  __syncthreads();

  // 5) flash combine across the 4 waves (all m equal -> sc == 1, exact)
  int qr = threadIdx.x & 31, cc = threadIdx.x >> 5;  // cc = dv chunk (0..7)
  float mw[4], M = -INFINITY;
#pragma unroll
  for (int w = 0; w < 4; ++w) { mw[w] = mlm[w][qr]; M = fmaxf(M, mw[w]); }
  float L = 0.f, O[8] = {};
#pragma unroll
  for (int w = 0; w < 4; ++w) {
    float sc = __builtin_exp2f(mw[w] - M);
    L += sc * mll[w][qr];
    short4v a = *reinterpret_cast<const short4v*>(&po[w][qr][cc * 8]);
    short4v b2 = *reinterpret_cast<const short4v*>(&po[w][qr][cc * 8 + 4]);
#pragma unroll
    for (int j = 0; j < 4; ++j) {
      O[j] += sc * bf2f(a[j]);
      O[4 + j] += sc * bf2f(b2[j]);
    }
  }
  float invL = 1.0f / L;
  U8 r8;
  r8.u[0] = pkrn(O[0] * invL, O[1] * invL);
  r8.u[1] = pkrn(O[2] * invL, O[3] * invL);
  r8.u[2] = pkrn(O[4] * invL, O[5] * invL);
  r8.u[3] = pkrn(O[6] * invL, O[7] * invL);
  *reinterpret_cast<short8*>(
      attn + (size_t)(b * S + q0 + qr) * D + h * DH + cc * 8) = r8.s;
}

}  // namespace

extern "C" void kernel_launch(void* const* d_in, const int* in_sizes, int n_in,
                              void* d_out, int out_size, void* d_ws, size_t ws_size,
                              hipStream_t stream) {
  const float* x    = (const float*)d_in[0];
  const float* prev = (const float*)d_in[1];
  const float* Wq   = (const float*)d_in[2];
  const float* Wk   = (const float*)d_in[3];
  const float* Wv   = (const float*)d_in[4];
  const float* Wo   = (const float*)d_in[5];
  const float* bq   = (const float*)d_in[6];
  const float* bk   = (const float*)d_in[7];
  const float* bv   = (const float*)d_in[8];
  const float* bo   = (const float*)d_in[9];
  const int* mask   = (const int*)d_in[10];
  float* out = (float*)d_out;
  char* ws = (char*)d_ws;

  constexpr size_t WSZ = (size_t)D * D * 2;      // 2 MB per bf16 weight
  constexpr size_t ASZ = (size_t)B * S * D * 2;  // 16 MB per bf16 activation
  short* WqT  = (short*)(ws);
  short* WkT  = (short*)(ws + WSZ);
  short* WvT  = (short*)(ws + 2 * WSZ);
  short* WoT  = (short*)(ws + 3 * WSZ);
  short* Qhb  = (short*)(ws + 4 * WSZ);
  short* K4   = (short*)(ws + 4 * WSZ + ASZ);
  short* V3   = (short*)(ws + 4 * WSZ + 2 * ASZ);
  short* xbf  = (short*)(ws + 4 * WSZ + 3 * ASZ);  // attn aliases xbf (dead after proj)
  short* pbf  = (short*)(ws + 4 * WSZ + 4 * ASZ);
  float* Knrm = (float*)(ws + 4 * WSZ + 5 * ASZ);  // B*H*NT floats (16 KB)
  short* attn = xbf;

  k_prep<<<dim3(4096 + 8192), 256, 0, stream>>>(
      Wq, Wk, Wv, Wo, x, prev, mask, WqT, WkT, WvT, WoT, xbf, pbf);
  k_proj_gemm<<<dim3(D / 128, S / 128, 3 * B), 256, 0, stream>>>(
      xbf, pbf, WqT, WkT, WvT, bq, bk, bv, mask, Qhb, K4, V3);
  k_knorm<<<dim3(NT, H, B), 64, 0, stream>>>(K4, mask, Knrm);
  k_attn<<<dim3(S / 32, H, B), 256, 0, stream>>>(
      Qhb, K4, V3, Knrm, mask, attn);
  k_out_gemm<<<dim3(D / 128, S / 128, B), 256, 0, stream>>>(
      x, attn, WoT, bo, mask, out);
}